// Round 1
// baseline (7992.426 us; speedup 1.0000x reference)
//
#include <hip/hip_runtime.h>
#include <hip/hip_bf16.h>

#define DI __device__ __forceinline__

static DI float sigmoidf_(float v){ return 1.f/(1.f+__expf(-v)); }

// ---------------------------------------------------------------------------
// Generic batched GEMM: C[M,N] = act(scale*(A @ B') + bias) (+ C_old if ACC)
// BT=true : B stored (N,K) row-major (weight layout, computes A @ W^T)
// BT=false: B stored (K,N) row-major (computes A @ B)
// grid = (N/BN, M/BM, batch); 256 threads.
// ---------------------------------------------------------------------------
template<int BM, int BN, int TM, int TN, int ACT, bool ACC, bool BT>
__global__ __launch_bounds__(256)
void gemm_k(const float* __restrict__ A, int lda, long sA,
            const float* __restrict__ B, int ldb, long sB,
            float* __restrict__ C, int ldc, long sC,
            const float* __restrict__ bias, float scale,
            int M, int N, int K)
{
  constexpr int BK = 16;
  const int bz = blockIdx.z;
  A += (long)bz * sA; B += (long)bz * sB; C += (long)bz * sC;
  const int bm = blockIdx.y * BM, bn = blockIdx.x * BN;
  __shared__ float As[BK][BM + 4];
  __shared__ float Bs[BK][BN + 4];
  const int tid = threadIdx.x;
  constexpr int NTX = BN / TN;
  const int tx = tid % NTX, ty = tid / NTX;
  float acc[TM][TN];
  #pragma unroll
  for (int i=0;i<TM;++i)
    #pragma unroll
    for (int j=0;j<TN;++j) acc[i][j]=0.f;

  for (int k0 = 0; k0 < K; k0 += BK) {
    #pragma unroll
    for (int p = 0; p < BM/64; ++p) {
      int r = (tid>>2) + p*64;
      int c = (tid&3)*4;
      float4 v = *(const float4*)(A + (long)(bm+r)*lda + k0 + c);
      As[c+0][r]=v.x; As[c+1][r]=v.y; As[c+2][r]=v.z; As[c+3][r]=v.w;
    }
    if (BT) {
      #pragma unroll
      for (int p = 0; p < BN/64; ++p) {
        int r = (tid>>2) + p*64;
        int c = (tid&3)*4;
        float4 v = *(const float4*)(B + (long)(bn+r)*ldb + k0 + c);
        Bs[c+0][r]=v.x; Bs[c+1][r]=v.y; Bs[c+2][r]=v.z; Bs[c+3][r]=v.w;
      }
    } else {
      #pragma unroll
      for (int p = 0; p < (BK*BN)/1024; ++p) {
        int idx = tid + p*256;
        int r = idx / (BN/4);
        int c = (idx % (BN/4))*4;
        float4 v = *(const float4*)(B + (long)(k0+r)*ldb + bn + c);
        *(float4*)&Bs[r][c] = v;
      }
    }
    __syncthreads();
    #pragma unroll
    for (int k = 0; k < BK; ++k) {
      float a[TM], b[TN];
      #pragma unroll
      for (int i=0;i<TM;i+=4) *(float4*)&a[i] = *(const float4*)&As[k][ty*TM+i];
      #pragma unroll
      for (int j=0;j<TN;j+=4) *(float4*)&b[j] = *(const float4*)&Bs[k][tx*TN+j];
      #pragma unroll
      for (int i=0;i<TM;++i)
        #pragma unroll
        for (int j=0;j<TN;++j)
          acc[i][j] = fmaf(a[i], b[j], acc[i][j]);
    }
    __syncthreads();
  }
  #pragma unroll
  for (int i=0;i<TM;++i) {
    const int m = bm + ty*TM + i;
    #pragma unroll
    for (int j=0;j<TN;++j) {
      const int n = bn + tx*TN + j;
      float v = acc[i][j]*scale;
      if (bias) v += bias[n];
      if (ACC)  v += C[(long)m*ldc + n];
      if (ACT==1)      v = sigmoidf_(v);
      else if (ACT==2) v = fmaxf(v, 0.f);
      else if (ACT==3) v = 0.5f*v*(1.f + erff(v*0.70710678118f));
      C[(long)m*ldc + n] = v;
    }
  }
}

// ---------------------------------------------------------------------------
// SSM scan: s_t = A*s_{t-1} + g_t*bx_t per (b,s); one wave per row, 16 t/lane,
// affine-compose shfl scan (A constant per s => segment map is (A^16, b)).
// grid = B*S = 1024 blocks of 64.
// ---------------------------------------------------------------------------
__global__ __launch_bounds__(64)
void scan_k(const float* __restrict__ G, const float* __restrict__ BX,
            const float* __restrict__ A_log, float* __restrict__ ST)
{
  const int b = blockIdx.x >> 7, s = blockIdx.x & 127;
  const int lane = threadIdx.x;
  const float Aa = __expf(A_log[s]);
  const long base = ((long)b*1024)*128 + s;
  float g[16], xv[16];
  const int t0 = lane*16;
  #pragma unroll
  for (int k=0;k<16;++k){
    g[k]  = G [base + (long)(t0+k)*128];
    xv[k] = BX[base + (long)(t0+k)*128];
  }
  float bl = 0.f;
  #pragma unroll
  for (int k=0;k<16;++k) bl = fmaf(Aa, bl, g[k]*xv[k]);
  const float A2v=Aa*Aa, A4v=A2v*A2v, A8v=A4v*A4v, A16=A8v*A8v;
  float a = A16, bb = bl;
  #pragma unroll
  for (int d=1; d<64; d<<=1) {
    float ap = __shfl_up(a, d);
    float bp = __shfl_up(bb, d);
    if (lane >= d) { bb = fmaf(bp, a, bb); a = ap * a; }
  }
  float carry = __shfl_up(bb, 1);
  if (lane == 0) carry = 0.f;
  float st = carry;
  #pragma unroll
  for (int k=0;k<16;++k) {
    st = fmaf(Aa, st, g[k]*xv[k]);
    ST[base + (long)(t0+k)*128] = st;
  }
}

// y += (D[h]+1)*x  (fuses D*x and the +x residual)
__global__ __launch_bounds__(256)
void add_dx_k(float* __restrict__ y, const float* __restrict__ x, const float* __restrict__ D)
{
  const long f = ((long)blockIdx.x*256 + threadIdx.x)*4;
  const int col = (int)(f & 1023);
  float4 yv = *(float4*)(y + f);
  const float4 xv = *(const float4*)(x + f);
  const float4 dv = *(const float4*)(D + col);
  yv.x = fmaf(dv.x+1.f, xv.x, yv.x);
  yv.y = fmaf(dv.y+1.f, xv.y, yv.y);
  yv.z = fmaf(dv.z+1.f, xv.z, yv.z);
  yv.w = fmaf(dv.w+1.f, xv.w, yv.w);
  *(float4*)(y+f) = yv;
}

// out = LN(a (+ b)) * g + be over H=1024. grid = rows, 256 threads.
__global__ __launch_bounds__(256)
void ln_k(const float* __restrict__ a, const float* __restrict__ b,
          const float* __restrict__ g, const float* __restrict__ be,
          float* __restrict__ out)
{
  const int row = blockIdx.x, tid = threadIdx.x;
  const long base = (long)row*1024 + tid*4;
  float4 v = *(const float4*)(a + base);
  if (b) {
    const float4 w = *(const float4*)(b + base);
    v.x+=w.x; v.y+=w.y; v.z+=w.z; v.w+=w.w;
  }
  float s  = v.x+v.y+v.z+v.w;
  float ss = v.x*v.x+v.y*v.y+v.z*v.z+v.w*v.w;
  #pragma unroll
  for (int d=32; d; d>>=1){ s += __shfl_xor(s,d); ss += __shfl_xor(ss,d); }
  __shared__ float rs[4], rss[4];
  const int w = tid>>6, lane = tid&63;
  if (lane==0){ rs[w]=s; rss[w]=ss; }
  __syncthreads();
  s  = rs[0]+rs[1]+rs[2]+rs[3];
  ss = rss[0]+rss[1]+rss[2]+rss[3];
  const float mean = s*(1.f/1024.f);
  const float var  = ss*(1.f/1024.f) - mean*mean;
  const float r = rsqrtf(var + 1e-5f);
  const float4 gv = *(const float4*)(g + tid*4);
  const float4 bv = *(const float4*)(be + tid*4);
  float4 o;
  o.x = (v.x-mean)*r*gv.x + bv.x;
  o.y = (v.y-mean)*r*gv.y + bv.y;
  o.z = (v.z-mean)*r*gv.z + bv.z;
  o.w = (v.w-mean)*r*gv.w + bv.w;
  *(float4*)(out + base) = o;
}

// ---------------------------------------------------------------------------
// Flash self-attention f32: NH=16, dh=64, T=1024. One q-row per thread,
// K/V tiles of 64 keys in LDS, branchy online softmax.
// grid = (4 qtiles, 16 heads, 8 batch), 256 threads.
// ---------------------------------------------------------------------------
__global__ __launch_bounds__(256)
void attn_self_k(const float* __restrict__ Q, const float* __restrict__ Kg,
                 const float* __restrict__ Vg, float* __restrict__ O)
{
  const int b = blockIdx.z, h = blockIdx.y, qt = blockIdx.x;
  const int tid = threadIdx.x;
  const long base = ((long)b*1024)*1024 + h*64;
  const long qrow = base + (long)(qt*256 + tid)*1024;
  float4 q4[16];
  #pragma unroll
  for (int i=0;i<16;++i) q4[i] = *(const float4*)(Q + qrow + i*4);
  float4 o4[16];
  #pragma unroll
  for (int i=0;i<16;++i) o4[i] = make_float4(0.f,0.f,0.f,0.f);
  float m = -1e30f, l = 0.f;
  __shared__ float4 Ks[64][16];
  __shared__ float4 Vs[64][16];
  for (int kt = 0; kt < 16; ++kt) {
    __syncthreads();
    #pragma unroll
    for (int p=0;p<4;++p){
      const int idx = tid + p*256;
      const int r = idx>>4, c = idx&15;
      const long off = base + (long)(kt*64+r)*1024 + c*4;
      Ks[r][c] = *(const float4*)(Kg + off);
      Vs[r][c] = *(const float4*)(Vg + off);
    }
    __syncthreads();
    for (int kk=0; kk<64; ++kk) {
      float s = 0.f;
      #pragma unroll
      for (int i=0;i<16;++i){
        const float4 kv = Ks[kk][i];
        s = fmaf(q4[i].x, kv.x, s); s = fmaf(q4[i].y, kv.y, s);
        s = fmaf(q4[i].z, kv.z, s); s = fmaf(q4[i].w, kv.w, s);
      }
      s *= 0.125f;
      if (s > m) {
        const float corr = __expf(m - s);
        m = s; l *= corr;
        #pragma unroll
        for (int i=0;i<16;++i){
          o4[i].x*=corr; o4[i].y*=corr; o4[i].z*=corr; o4[i].w*=corr;
        }
      }
      const float p = __expf(s - m);
      l += p;
      #pragma unroll
      for (int i=0;i<16;++i){
        const float4 vv = Vs[kk][i];
        o4[i].x = fmaf(p, vv.x, o4[i].x);
        o4[i].y = fmaf(p, vv.y, o4[i].y);
        o4[i].z = fmaf(p, vv.z, o4[i].z);
        o4[i].w = fmaf(p, vv.w, o4[i].w);
      }
    }
  }
  const float inv = 1.f/l;
  #pragma unroll
  for (int i=0;i<16;++i){
    float4 o;
    o.x=o4[i].x*inv; o.y=o4[i].y*inv; o.z=o4[i].z*inv; o.w=o4[i].w*inv;
    *(float4*)(O + qrow + i*4) = o;
  }
}

// softmax over rows of 256, one wave per row
__global__ __launch_bounds__(64)
void softmax256_k(float* __restrict__ S)
{
  float* p = S + (long)blockIdx.x*256 + threadIdx.x*4;
  float4 v = *(float4*)p;
  float m = fmaxf(fmaxf(v.x,v.y), fmaxf(v.z,v.w));
  #pragma unroll
  for (int d=32; d; d>>=1) m = fmaxf(m, __shfl_xor(m, d));
  v.x=__expf(v.x-m); v.y=__expf(v.y-m); v.z=__expf(v.z-m); v.w=__expf(v.w-m);
  float s = v.x+v.y+v.z+v.w;
  #pragma unroll
  for (int d=32; d; d>>=1) s += __shfl_xor(s, d);
  const float inv = 1.f/s;
  v.x*=inv; v.y*=inv; v.z*=inv; v.w*=inv;
  *(float4*)p = v;
}

// x3 = x2*(1+sigmoid(gp)) + (1-sigmoid(gp))*cb
__global__ __launch_bounds__(256)
void gate_combine_k(const float* __restrict__ x2, const float* __restrict__ cb,
                    const float* __restrict__ gp, float* __restrict__ x3)
{
  const long i = ((long)blockIdx.x*256 + threadIdx.x)*4;
  const float4 a = *(const float4*)(x2+i);
  const float4 c = *(const float4*)(cb+i);
  const float4 g = *(const float4*)(gp+i);
  float4 o; float gg;
  gg = sigmoidf_(g.x); o.x = fmaf(a.x, 1.f+gg, (1.f-gg)*c.x);
  gg = sigmoidf_(g.y); o.y = fmaf(a.y, 1.f+gg, (1.f-gg)*c.y);
  gg = sigmoidf_(g.z); o.z = fmaf(a.z, 1.f+gg, (1.f-gg)*c.z);
  gg = sigmoidf_(g.w); o.w = fmaf(a.w, 1.f+gg, (1.f-gg)*c.w);
  *(float4*)(x3+i) = o;
}

#define G128(ACT,ACC) gemm_k<128,128,8,8,ACT,ACC,true>
#define G64(ACT,ACC)  gemm_k<64,64,4,4,ACT,ACC,true>
#define G64NN(ACC)    gemm_k<64,64,4,4,0,ACC,false>

extern "C" void kernel_launch(void* const* d_in, const int* in_sizes, int n_in,
                              void* d_out, int out_size, void* d_ws, size_t ws_size,
                              hipStream_t stream)
{
  const float* x         = (const float*)d_in[0];
  const float* mem0      = (const float*)d_in[1];
  const float* mem1      = (const float*)d_in[2];
  const float* mem2      = (const float*)d_in[3];
  const float* A_log     = (const float*)d_in[4];
  const float* B_w       = (const float*)d_in[5];
  const float* C_w       = (const float*)d_in[6];
  const float* Dv        = (const float*)d_in[7];
  const float* sgate_w   = (const float*)d_in[8];
  const float* sgate_b   = (const float*)d_in[9];
  const float* outp_w    = (const float*)d_in[10];
  const float* outp_b    = (const float*)d_in[11];
  const float* sln_g     = (const float*)d_in[12];
  const float* sln_b     = (const float*)d_in[13];
  const float* attn_in_w = (const float*)d_in[14];
  const float* attn_in_b = (const float*)d_in[15];
  const float* attn_out_w= (const float*)d_in[16];
  const float* attn_out_b= (const float*)d_in[17];
  const float* cw1[3] = {(const float*)d_in[18], (const float*)d_in[22], (const float*)d_in[26]};
  const float* cb1[3] = {(const float*)d_in[19], (const float*)d_in[23], (const float*)d_in[27]};
  const float* cw2[3] = {(const float*)d_in[20], (const float*)d_in[24], (const float*)d_in[28]};
  const float* cb2[3] = {(const float*)d_in[21], (const float*)d_in[25], (const float*)d_in[29]};
  const float* retr_in_w = (const float*)d_in[30];
  const float* retr_in_b = (const float*)d_in[31];
  const float* retr_out_w= (const float*)d_in[32];
  const float* retr_out_b= (const float*)d_in[33];
  const float* mg_w  = (const float*)d_in[34];
  const float* mg_b  = (const float*)d_in[35];
  const float* ffn_w1= (const float*)d_in[36];
  const float* ffn_b1= (const float*)d_in[37];
  const float* ffn_w2= (const float*)d_in[38];
  const float* ffn_b2= (const float*)d_in[39];
  const float* n1_g = (const float*)d_in[40];
  const float* n1_b = (const float*)d_in[41];
  const float* n2_g = (const float*)d_in[42];
  const float* n2_b = (const float*)d_in[43];
  const float* n3_g = (const float*)d_in[44];
  const float* n3_b = (const float*)d_in[45];
  float* out = (float*)d_out;

  const long TOK = (long)8192*1024;          // 8M floats = 32MB
  float* W  = (float*)d_ws;
  float* A0 = W;
  float* A1 = W + TOK;
  float* A2 = W + 2*TOK;
  float* A3 = W + 3*TOK;
  float* A4 = W + 4*TOK;
  float* G  = W + 5*TOK;                      // 8192x128
  float* BX = G  + (long)8192*128;
  float* ST = BX + (long)8192*128;
  float* HB = ST + (long)8192*128;            // 2048x1024 max
  float* CB = HB + (long)2048*1024;
  float* KR = CB + (long)2048*1024;
  float* VR = KR + (long)2048*1024;
  const size_t need = (size_t)((VR + (long)2048*1024) - W) * 4;
  if (ws_size < need) return;  // workspace too small; fail loudly via mismatch

  // 1-2: gate = sigmoid(x@sgate_w^T+b); Bx = x@B_w^T
  G64(1,false)<<<dim3(2,128,1),256,0,stream>>>(x,1024,0, sgate_w,1024,0, G,128,0, sgate_b, 1.f, 8192,128,1024);
  G64(0,false)<<<dim3(2,128,1),256,0,stream>>>(x,1024,0, B_w,1024,0, BX,128,0, nullptr, 1.f, 8192,128,1024);
  // 3: scan
  scan_k<<<1024,64,0,stream>>>(G,BX,A_log,ST);
  // 4: y = states@C_w^T -> A0
  G128(0,false)<<<dim3(8,64,1),256,0,stream>>>(ST,128,0, C_w,128,0, A0,1024,0, nullptr, 1.f, 8192,1024,128);
  // 5: u1 = y + (D+1)*x
  add_dx_k<<<8192,256,0,stream>>>(A0, x, Dv);
  // 6: t = LN(u1; sln) -> A1
  ln_k<<<8192,256,0,stream>>>(A0, nullptr, sln_g, sln_b, A1);
  // 7: x_state = t@outp_w^T + outp_b -> A2
  G128(0,false)<<<dim3(8,64,1),256,0,stream>>>(A1,1024,0, outp_w,1024,0, A2,1024,0, outp_b, 1.f, 8192,1024,1024);
  // 8: x1 = LN(x + x_state; n1) -> A1
  ln_k<<<8192,256,0,stream>>>(x, A2, n1_g, n1_b, A1);
  // 9: Q,K,V -> A0,A2,A3
  G128(0,false)<<<dim3(8,64,1),256,0,stream>>>(A1,1024,0, attn_in_w,              1024,0, A0,1024,0, attn_in_b,      1.f, 8192,1024,1024);
  G128(0,false)<<<dim3(8,64,1),256,0,stream>>>(A1,1024,0, attn_in_w+(long)1024*1024,1024,0, A2,1024,0, attn_in_b+1024, 1.f, 8192,1024,1024);
  G128(0,false)<<<dim3(8,64,1),256,0,stream>>>(A1,1024,0, attn_in_w+(long)2048*1024,1024,0, A3,1024,0, attn_in_b+2048, 1.f, 8192,1024,1024);
  // 10: O = flash(Q,K,V) -> A4
  attn_self_k<<<dim3(4,16,8),256,0,stream>>>(A0,A2,A3,A4);
  // 11: ao = O@attn_out_w^T + b -> A0
  G128(0,false)<<<dim3(8,64,1),256,0,stream>>>(A4,1024,0, attn_out_w,1024,0, A0,1024,0, attn_out_b, 1.f, 8192,1024,1024);
  // 12: x2 = LN(x1 + ao; n2) -> A2
  ln_k<<<8192,256,0,stream>>>(A1, A0, n2_g, n2_b, A2);
  // 13: Qr = x2@wq_r^T + b -> A1
  G128(0,false)<<<dim3(8,64,1),256,0,stream>>>(A2,1024,0, retr_in_w,1024,0, A1,1024,0, retr_in_b, 1.f, 8192,1024,1024);
  // 14: retrieval comps; O accumulated into A4, scores in A3
  const float* mptr[3] = {mem0, mem1 + (long)256*1024, mem2 + (long)768*1024};
  const long   mstr[3] = {(long)256*1024, (long)512*1024, (long)1024*1024};
  const int    cdim[3] = {1024,512,256};
  for (int i=0;i<3;++i) {
    const int c = cdim[i];
    G64(2,false)<<<dim3(c/64,4,8),256,0,stream>>>(mptr[i],1024,mstr[i], cw1[i],1024,0, HB,c,(long)256*c, cb1[i], 1.f, 256,c,1024);
    G64(0,false)<<<dim3(16,4,8),256,0,stream>>>(HB,c,(long)256*c, cw2[i],c,0, CB,1024,(long)256*1024, cb2[i], 1.f, 256,1024,c);
    G128(0,false)<<<dim3(8,16,1),256,0,stream>>>(CB,1024,0, retr_in_w+(long)1024*1024,1024,0, KR,1024,0, retr_in_b+1024, 1.f, 2048,1024,1024);
    G128(0,false)<<<dim3(8,16,1),256,0,stream>>>(CB,1024,0, retr_in_w+(long)2048*1024,1024,0, VR,1024,0, retr_in_b+2048, 1.f, 2048,1024,1024);
    for (int h=0;h<4;++h)
      G64(0,false)<<<dim3(4,16,8),256,0,stream>>>(A1+h*256,1024,(long)1024*1024, KR+h*256,1024,(long)256*1024,
          A3+(long)h*1024*256,256,(long)4*1024*256, nullptr, 0.0625f, 1024,256,256);
    softmax256_k<<<32768,64,0,stream>>>(A3);
    for (int h=0;h<4;++h) {
      if (i==0)
        G64NN(false)<<<dim3(4,16,8),256,0,stream>>>(A3+(long)h*1024*256,256,(long)4*1024*256, VR+h*256,1024,(long)256*1024,
            A4+h*256,1024,(long)1024*1024, nullptr, 1.f, 1024,256,256);
      else
        G64NN(true)<<<dim3(4,16,8),256,0,stream>>>(A3+(long)h*1024*256,256,(long)4*1024*256, VR+h*256,1024,(long)256*1024,
            A4+h*256,1024,(long)1024*1024, nullptr, 1.f, 1024,256,256);
    }
  }
  // 15: combined = (Osum/3)@retr_out_w^T + b -> A0
  G128(0,false)<<<dim3(8,64,1),256,0,stream>>>(A4,1024,0, retr_out_w,1024,0, A0,1024,0, retr_out_b, 1.f/3.f, 8192,1024,1024);
  // 16: gpre = x2@mgA^T + mg_b ; gpre += combined@mgB^T  -> A1
  G128(0,false)<<<dim3(8,64,1),256,0,stream>>>(A2,1024,0, mg_w,     2048,0, A1,1024,0, mg_b,    1.f, 8192,1024,1024);
  G128(0,true )<<<dim3(8,64,1),256,0,stream>>>(A0,1024,0, mg_w+1024,2048,0, A1,1024,0, nullptr, 1.f, 8192,1024,1024);
  // 17: x3 -> A3
  gate_combine_k<<<8192,256,0,stream>>>(A2, A0, A1, A3);
  // 18: FFN chunked (hidden 2048x4096 in A1), f -> A0
  for (int cch=0; cch<4; ++cch) {
    const long off = (long)cch*2048*1024;
    G128(3,false)<<<dim3(32,16,1),256,0,stream>>>(A3+off,1024,0, ffn_w1,1024,0, A1,4096,0, ffn_b1, 1.f, 2048,4096,1024);
    G128(0,false)<<<dim3(8,16,1),256,0,stream>>>(A1,4096,0, ffn_w2,4096,0, A0+off,1024,0, ffn_b2, 1.f, 2048,1024,4096);
  }
  // 19: out = LN(x3 + ffn; n3)
  ln_k<<<8192,256,0,stream>>>(A3, A0, n3_g, n3_b, out);
}

// Round 3
// 2297.176 us; speedup vs baseline: 3.4792x; 3.4792x over previous
//
#include <hip/hip_runtime.h>
#include <hip/hip_bf16.h>

typedef unsigned short u16;
typedef _Float16 f16;
typedef _Float16 h8 __attribute__((ext_vector_type(8)));
typedef float f32x4 __attribute__((ext_vector_type(4)));
typedef unsigned short us8 __attribute__((ext_vector_type(8)));

#define DI __device__ __forceinline__

DI float sigmoidf_(float v){ return 1.f/(1.f+__expf(-v)); }
DI u16 f2h(float v){ f16 h=(f16)v; u16 u; __builtin_memcpy(&u,&h,2); return u; }
DI float h2f(u16 u){ f16 h; __builtin_memcpy(&h,&u,2); return (float)h; }

DI void gl16(const void* g, void* l){
  __builtin_amdgcn_global_load_lds((const __attribute__((address_space(1))) unsigned int*)g,
                                   (__attribute__((address_space(3))) unsigned int*)l, 16, 0, 0);
}

// ---------------------------------------------------------------------------
// FP16 MFMA GEMM (NT): C[M,N] = act(scale*(A @ B^T) + bias), A[M,K] f16,
// B[N,K] f16 (weight layout). 128x128 tile, BK=32, 4 waves (2x2), each wave
// 64x64 via 4x4 frags of v_mfma_f32_16x16x32_f16. global_load_lds width-16
// with pre-swizzled global source; XOR-swizzled ds_read_b128 fragments.
// OUT: 0=f32 C, 1=f16 Ch, 2=dual f32+f16, 3=f16 transposed (Ch[col*ldch+row]).
// ACT: 0=none 1=sigmoid 2=relu 3=gelu(exact) 4=sigmoid-gate-combine(aux1,aux2)
// ZH: 1 => z batches via sXb only; 4 => z=(b<<2|h), offsets b*sXb + h*sXh.
// ---------------------------------------------------------------------------
template<int ACT, int OUT, bool ACC, int ZH>
__global__ __launch_bounds__(256)
void hgemm_k(const u16* A, long sAb, long sAh, int lda,
             const u16* B, long sBb, long sBh, int ldb,
             float* Cf, u16* Ch, long sCb, long sCh, int ldc, int ldch,
             const float* __restrict__ bias,
             const float* __restrict__ aux1, const float* __restrict__ aux2,
             float scale, int K)
{
  const int z = blockIdx.z;
  long zb, zh;
  if (ZH==4){ zb = z>>2; zh = z&3; } else { zb = z; zh = 0; }
  A += zb*sAb + zh*sAh;
  B += zb*sBb + zh*sBh;
  if (OUT==0 || OUT==2) Cf += zb*sCb + zh*sCh;
  if (OUT==1 || OUT==3) Ch += zb*sCb + zh*sCh;

  const int bm = blockIdx.y*128, bn = blockIdx.x*128;
  __shared__ u16 Ash[128*32];
  __shared__ u16 Bsh[128*32];
  const int tid = threadIdx.x, wid = tid>>6, lane = tid&63;
  const int wr = wid>>1, wc = wid&1;

  f32x4 acc[4][4];
  #pragma unroll
  for (int m=0;m<4;++m)
    #pragma unroll
    for (int n=0;n<4;++n)
      #pragma unroll
      for (int r=0;r<4;++r) acc[m][n][r]=0.f;

  const int off0 = wid*2048 + lane*16;   // byte offset in 8KB tile (+is*1024)
  const char* Ab = (const char*)A;
  const char* Bb = (const char*)B;

  for (int k0=0; k0<K; k0+=32){
    __syncthreads();
    #pragma unroll
    for (int is=0; is<2; ++is){
      const int off = off0 + is*1024;
      const int row = off>>6;
      const int sl  = (off&63) ^ ((row&3)<<4);   // pre-swizzled source slot
      gl16(Ab + ((long)(bm+row)*lda + k0)*2 + sl, (char*)Ash + off);
      gl16(Bb + ((long)(bn+row)*ldb + k0)*2 + sl, (char*)Bsh + off);
    }
    asm volatile("s_waitcnt vmcnt(0)" ::: "memory");
    __syncthreads();

    const int ko = lane>>4, li = lane&15;
    h8 af[4], bf[4];
    #pragma unroll
    for (int m=0;m<4;++m){
      const int row = wr*64 + m*16 + li;
      af[m] = *(const h8*)((const char*)Ash + row*64 + ((ko^(row&3))<<4));
    }
    #pragma unroll
    for (int n=0;n<4;++n){
      const int row = wc*64 + n*16 + li;
      bf[n] = *(const h8*)((const char*)Bsh + row*64 + ((ko^(row&3))<<4));
    }
    #pragma unroll
    for (int m=0;m<4;++m)
      #pragma unroll
      for (int n=0;n<4;++n)
        acc[m][n] = __builtin_amdgcn_mfma_f32_16x16x32_f16(af[m], bf[n], acc[m][n], 0,0,0);
  }

  const int li = lane&15;
  const int r0 = bm + wr*64 + (lane>>4)*4;
  const int c0 = bn + wc*64 + li;
  #pragma unroll
  for (int n=0;n<4;++n){
    const int col = c0 + n*16;
    const float bv = bias ? bias[col] : 0.f;
    #pragma unroll
    for (int m=0;m<4;++m){
      #pragma unroll
      for (int r=0;r<4;++r){
        const int row = r0 + m*16 + r;
        float v = acc[m][n][r]*scale + bv;
        if (ACT==1)      v = sigmoidf_(v);
        else if (ACT==2) v = fmaxf(v,0.f);
        else if (ACT==3) v = 0.5f*v*(1.f+erff(v*0.70710678118f));
        else if (ACT==4){
          const long ix = (long)row*ldc + col;
          const float gg = sigmoidf_(v);
          v = fmaf(aux1[ix], 1.f+gg, (1.f-gg)*aux2[ix]);
        }
        if (OUT==0){
          const long ix = (long)row*ldc + col;
          Cf[ix] = ACC ? Cf[ix]+v : v;
        } else if (OUT==1){
          Ch[(long)row*ldch + col] = f2h(v);
        } else if (OUT==2){
          Cf[(long)row*ldc + col] = v;
          Ch[(long)row*ldch + col] = f2h(v);
        } else {
          Ch[(long)col*ldch + row] = f2h(v);
        }
      }
    }
  }
}

// ---------------------------------------------------------------------------
// SSM scan (unchanged math, f16 output)
// ---------------------------------------------------------------------------
__global__ __launch_bounds__(64)
void scan_k(const float* __restrict__ G, const float* __restrict__ BX,
            const float* __restrict__ A_log, u16* __restrict__ ST)
{
  const int b = blockIdx.x >> 7, s = blockIdx.x & 127;
  const int lane = threadIdx.x;
  const float Aa = __expf(A_log[s]);
  const long base = ((long)b*1024)*128 + s;
  float g[16], xv[16];
  const int t0 = lane*16;
  #pragma unroll
  for (int k=0;k<16;++k){
    g[k]  = G [base + (long)(t0+k)*128];
    xv[k] = BX[base + (long)(t0+k)*128];
  }
  float bl = 0.f;
  #pragma unroll
  for (int k=0;k<16;++k) bl = fmaf(Aa, bl, g[k]*xv[k]);
  const float A2v=Aa*Aa, A4v=A2v*A2v, A8v=A4v*A4v, A16=A8v*A8v;
  float a = A16, bb = bl;
  #pragma unroll
  for (int d=1; d<64; d<<=1) {
    float ap = __shfl_up(a, d);
    float bp = __shfl_up(bb, d);
    if (lane >= d) { bb = fmaf(bp, a, bb); a = ap * a; }
  }
  float carry = __shfl_up(bb, 1);
  if (lane == 0) carry = 0.f;
  float st = carry;
  #pragma unroll
  for (int k=0;k<16;++k) {
    st = fmaf(Aa, st, g[k]*xv[k]);
    ST[base + (long)(t0+k)*128] = f2h(st);
  }
}

__global__ __launch_bounds__(256)
void add_dx_k(float* __restrict__ y, const float* __restrict__ x, const float* __restrict__ D)
{
  const long f = ((long)blockIdx.x*256 + threadIdx.x)*4;
  const int col = (int)(f & 1023);
  float4 yv = *(float4*)(y + f);
  const float4 xv = *(const float4*)(x + f);
  const float4 dv = *(const float4*)(D + col);
  yv.x = fmaf(dv.x+1.f, xv.x, yv.x);
  yv.y = fmaf(dv.y+1.f, xv.y, yv.y);
  yv.z = fmaf(dv.z+1.f, xv.z, yv.z);
  yv.w = fmaf(dv.w+1.f, xv.w, yv.w);
  *(float4*)(y+f) = yv;
}

// LN over H=1024: outF (f32, optional) and outH (f16, optional, leading dim ldH)
__global__ __launch_bounds__(256)
void ln_k(const float* __restrict__ a, const float* __restrict__ b,
          const float* __restrict__ g, const float* __restrict__ be,
          float* __restrict__ outF, u16* __restrict__ outH, int ldH)
{
  const int row = blockIdx.x, tid = threadIdx.x;
  const long base = (long)row*1024 + tid*4;
  float4 v = *(const float4*)(a + base);
  if (b) {
    const float4 w = *(const float4*)(b + base);
    v.x+=w.x; v.y+=w.y; v.z+=w.z; v.w+=w.w;
  }
  float s  = v.x+v.y+v.z+v.w;
  float ss = v.x*v.x+v.y*v.y+v.z*v.z+v.w*v.w;
  #pragma unroll
  for (int d=32; d; d>>=1){ s += __shfl_xor(s,d); ss += __shfl_xor(ss,d); }
  __shared__ float rs[4], rss[4];
  const int w = tid>>6, lane = tid&63;
  if (lane==0){ rs[w]=s; rss[w]=ss; }
  __syncthreads();
  s  = rs[0]+rs[1]+rs[2]+rs[3];
  ss = rss[0]+rss[1]+rss[2]+rss[3];
  const float mean = s*(1.f/1024.f);
  const float var  = ss*(1.f/1024.f) - mean*mean;
  const float r = rsqrtf(var + 1e-5f);
  const float4 gv = *(const float4*)(g + tid*4);
  const float4 bv = *(const float4*)(be + tid*4);
  float4 o;
  o.x = (v.x-mean)*r*gv.x + bv.x;
  o.y = (v.y-mean)*r*gv.y + bv.y;
  o.z = (v.z-mean)*r*gv.z + bv.z;
  o.w = (v.w-mean)*r*gv.w + bv.w;
  if (outF) *(float4*)(outF + base) = o;
  if (outH){
    ushort4 h; h.x=f2h(o.x); h.y=f2h(o.y); h.z=f2h(o.z); h.w=f2h(o.w);
    *(ushort4*)(outH + (long)row*ldH + tid*4) = h;
  }
}

// ---------------------------------------------------------------------------
// Flash self-attention: f16 Q/K/V in, f16 O out (in-place over Q region).
// QO/O: [8192,1024] f16. KV: [8192,2048] f16, K = cols 0..1023, V = cols 1024..
// ---------------------------------------------------------------------------
__global__ __launch_bounds__(256)
void attn_self_k(const u16* QO, const u16* __restrict__ KV, u16* O)
{
  const int b = blockIdx.z, h = blockIdx.y, qt = blockIdx.x;
  const int tid = threadIdx.x;
  const long qoff = ((long)(b*1024 + qt*256 + tid))*1024 + h*64;
  const long kvbase = (long)b*1024*2048 + h*64;
  float4 q4[16];
  #pragma unroll
  for (int i=0;i<16;++i){
    ushort4 u = *(const ushort4*)(QO + qoff + i*4);
    q4[i] = make_float4(h2f(u.x), h2f(u.y), h2f(u.z), h2f(u.w));
  }
  float4 o4[16];
  #pragma unroll
  for (int i=0;i<16;++i) o4[i] = make_float4(0.f,0.f,0.f,0.f);
  float m = -1e30f, l = 0.f;
  __shared__ float4 Ks[64][16];
  __shared__ float4 Vs[64][16];
  for (int kt = 0; kt < 16; ++kt) {
    __syncthreads();
    #pragma unroll
    for (int p=0;p<2;++p){
      const int idx = tid + p*256;
      const int r = idx>>3, cc = idx&7;
      const long off = kvbase + (long)(kt*64+r)*2048 + cc*8;
      us8 ku = *(const us8*)(KV + off);
      us8 vu = *(const us8*)(KV + off + 1024);
      Ks[r][cc*2+0] = make_float4(h2f(ku[0]),h2f(ku[1]),h2f(ku[2]),h2f(ku[3]));
      Ks[r][cc*2+1] = make_float4(h2f(ku[4]),h2f(ku[5]),h2f(ku[6]),h2f(ku[7]));
      Vs[r][cc*2+0] = make_float4(h2f(vu[0]),h2f(vu[1]),h2f(vu[2]),h2f(vu[3]));
      Vs[r][cc*2+1] = make_float4(h2f(vu[4]),h2f(vu[5]),h2f(vu[6]),h2f(vu[7]));
    }
    __syncthreads();
    for (int kk=0; kk<64; ++kk) {
      float s = 0.f;
      #pragma unroll
      for (int i=0;i<16;++i){
        const float4 kv = Ks[kk][i];
        s = fmaf(q4[i].x, kv.x, s); s = fmaf(q4[i].y, kv.y, s);
        s = fmaf(q4[i].z, kv.z, s); s = fmaf(q4[i].w, kv.w, s);
      }
      s *= 0.125f;
      if (s > m) {
        const float corr = __expf(m - s);
        m = s; l *= corr;
        #pragma unroll
        for (int i=0;i<16;++i){
          o4[i].x*=corr; o4[i].y*=corr; o4[i].z*=corr; o4[i].w*=corr;
        }
      }
      const float p = __expf(s - m);
      l += p;
      #pragma unroll
      for (int i=0;i<16;++i){
        const float4 vv = Vs[kk][i];
        o4[i].x = fmaf(p, vv.x, o4[i].x);
        o4[i].y = fmaf(p, vv.y, o4[i].y);
        o4[i].z = fmaf(p, vv.z, o4[i].z);
        o4[i].w = fmaf(p, vv.w, o4[i].w);
      }
    }
  }
  const float inv = 1.f/l;
  #pragma unroll
  for (int i=0;i<16;++i){
    ushort4 o;
    o.x = f2h(o4[i].x*inv); o.y = f2h(o4[i].y*inv);
    o.z = f2h(o4[i].z*inv); o.w = f2h(o4[i].w*inv);
    *(ushort4*)(O + qoff + i*4) = o;
  }
}

// softmax over rows of 256, f16 in/out in place, one wave per row
__global__ __launch_bounds__(64)
void softmax256h_k(u16* __restrict__ S)
{
  u16* p = S + (long)blockIdx.x*256 + threadIdx.x*4;
  ushort4 u = *(ushort4*)p;
  float v0=h2f(u.x), v1=h2f(u.y), v2=h2f(u.z), v3=h2f(u.w);
  float m = fmaxf(fmaxf(v0,v1), fmaxf(v2,v3));
  #pragma unroll
  for (int d=32; d; d>>=1) m = fmaxf(m, __shfl_xor(m, d));
  v0=__expf(v0-m); v1=__expf(v1-m); v2=__expf(v2-m); v3=__expf(v3-m);
  float s = v0+v1+v2+v3;
  #pragma unroll
  for (int d=32; d; d>>=1) s += __shfl_xor(s, d);
  const float inv = 1.f/s;
  ushort4 o; o.x=f2h(v0*inv); o.y=f2h(v1*inv); o.z=f2h(v2*inv); o.w=f2h(v3*inv);
  *(ushort4*)p = o;
}

// batched f32 -> f16 conversion (up to 16 tensors per launch)
struct CvtB { const float* s[16]; u16* d[16]; int n[16]; int start[16]; int cnt; };
__global__ __launch_bounds__(256)
void cvtb_k(CvtB cb)
{
  const int bid = blockIdx.x;
  int t = 0;
  #pragma unroll 1
  for (int i=1;i<16;++i) if (i<cb.cnt && bid>=cb.start[i]) t = i;
  const long idx = ((long)(bid - cb.start[t])*256 + threadIdx.x)*4;
  if (idx >= cb.n[t]) return;
  const float4 v = *(const float4*)(cb.s[t]+idx);
  ushort4 o; o.x=f2h(v.x); o.y=f2h(v.y); o.z=f2h(v.z); o.w=f2h(v.w);
  *(ushort4*)(cb.d[t]+idx) = o;
}

__global__ __launch_bounds__(256)
void cvt_k(const float* __restrict__ s, u16* __restrict__ d, long n)
{
  const long idx = ((long)blockIdx.x*256 + threadIdx.x)*4;
  if (idx >= n) return;
  const float4 v = *(const float4*)(s+idx);
  ushort4 o; o.x=f2h(v.x); o.y=f2h(v.y); o.z=f2h(v.z); o.w=f2h(v.w);
  *(ushort4*)(d+idx) = o;
}

extern "C" void kernel_launch(void* const* d_in, const int* in_sizes, int n_in,
                              void* d_out, int out_size, void* d_ws, size_t ws_size,
                              hipStream_t stream)
{
  const float* x         = (const float*)d_in[0];
  const float* mem0      = (const float*)d_in[1];
  const float* mem1      = (const float*)d_in[2];
  const float* mem2      = (const float*)d_in[3];
  const float* A_log     = (const float*)d_in[4];
  const float* B_w       = (const float*)d_in[5];
  const float* C_w       = (const float*)d_in[6];
  const float* Dv        = (const float*)d_in[7];
  const float* sgate_w   = (const float*)d_in[8];
  const float* sgate_b   = (const float*)d_in[9];
  const float* outp_w    = (const float*)d_in[10];
  const float* outp_b    = (const float*)d_in[11];
  const float* sln_g     = (const float*)d_in[12];
  const float* sln_b     = (const float*)d_in[13];
  const float* attn_in_w = (const float*)d_in[14];
  const float* attn_in_b = (const float*)d_in[15];
  const float* attn_out_w= (const float*)d_in[16];
  const float* attn_out_b= (const float*)d_in[17];
  const float* cw1[3] = {(const float*)d_in[18], (const float*)d_in[22], (const float*)d_in[26]};
  const float* cb1[3] = {(const float*)d_in[19], (const float*)d_in[23], (const float*)d_in[27]};
  const float* cw2[3] = {(const float*)d_in[20], (const float*)d_in[24], (const float*)d_in[28]};
  const float* cb2[3] = {(const float*)d_in[21], (const float*)d_in[25], (const float*)d_in[29]};
  const float* retr_in_w = (const float*)d_in[30];
  const float* retr_in_b = (const float*)d_in[31];
  const float* retr_out_w= (const float*)d_in[32];
  const float* retr_out_b= (const float*)d_in[33];
  const float* mg_w  = (const float*)d_in[34];
  const float* mg_b  = (const float*)d_in[35];
  const float* ffn_w1= (const float*)d_in[36];
  const float* ffn_b1= (const float*)d_in[37];
  const float* ffn_w2= (const float*)d_in[38];
  const float* ffn_b2= (const float*)d_in[39];
  const float* n1_g = (const float*)d_in[40];
  const float* n1_b = (const float*)d_in[41];
  const float* n2_g = (const float*)d_in[42];
  const float* n2_b = (const float*)d_in[43];
  const float* n3_g = (const float*)d_in[44];
  const float* n3_b = (const float*)d_in[45];
  float* out = (float*)d_out;

  // ---- workspace layout ----
  const long M8 = 8388608;     // 8192*1024
  float* A0 = (float*)d_ws;
  float* A1 = A0 + M8;
  float* A2 = A1 + M8;
  float* G  = A2 + M8;                 // 8192*128
  float* BX = G + 1048576;
  u16* U    = (u16*)(BX + 1048576);
  u16* T0   = U;                       // 8M f16
  u16* T1   = T0 + M8;                 // 8M f16 (xb / Q->O / P / OCb)
  u16* CAT  = T1 + M8;                 // 8192 x 2048 f16
  u16* STb  = CAT + 2*M8;              // 8192*128
  u16* T2   = STb + 1048576;           // 2048*1024
  u16* T3   = T2 + 2097152;
  u16* T4   = T3 + 2097152;
  u16* T5   = T4 + 2097152;            // VT [8][1024][256]
  u16* MB0  = T5 + 2097152;            // mem f16 [2048,1024] x3
  u16* MB1  = MB0 + 2097152;
  u16* MB2  = MB1 + 2097152;
  u16* Wb   = MB2 + 2097152;
  u16* wp   = Wb;
  auto nx = [&](long n){ u16* p = wp; wp += n; return p; };
  u16* w_sg  = nx(131072);
  u16* w_Bw  = nx(131072);
  u16* w_Cw  = nx(131072);
  u16* w_op  = nx(1048576);
  u16* w_ai  = nx(3145728);
  u16* w_ao  = nx(1048576);
  u16* w_ri  = nx(3145728);
  u16* w_ro  = nx(1048576);
  u16* w_mg  = nx(2097152);
  u16* w_f1  = nx(4194304);
  u16* w_f2  = nx(4194304);
  u16* w_c1[3] = {nx(1048576), nx(524288), nx(262144)};
  u16* w_c2[3] = {nx(1048576), nx(524288), nx(262144)};
  u16* FH = (u16*)A2;                  // FFN hidden overlays A2 (4096x4096 f16)
  const size_t need = (size_t)((char*)wp - (char*)d_ws);
  if (ws_size < need) return;

  // ---- weight / input conversions to f16 ----
  {
    CvtB cb; int k = 0, blk = 0;
    auto flush = [&](){
      if (k){ cb.cnt = k; cvtb_k<<<blk,256,0,stream>>>(cb); k = 0; blk = 0; }
    };
    auto push = [&](const float* s, u16* d, long n){
      if (k == 16) flush();
      cb.s[k]=s; cb.d[k]=d; cb.n[k]=(int)n; cb.start[k]=blk; blk += (int)(n/1024); ++k;
    };
    push(sgate_w, w_sg, 131072); push(B_w, w_Bw, 131072); push(C_w, w_Cw, 131072);
    push(outp_w, w_op, 1048576); push(attn_in_w, w_ai, 3145728);
    push(attn_out_w, w_ao, 1048576); push(retr_in_w, w_ri, 3145728);
    push(retr_out_w, w_ro, 1048576); push(mg_w, w_mg, 2097152);
    push(ffn_w1, w_f1, 4194304); push(ffn_w2, w_f2, 4194304);
    for (int i=0;i<3;++i) push(cw1[i], w_c1[i], (long)(1048576>>i));
    for (int i=0;i<3;++i) push(cw2[i], w_c2[i], (long)(1048576>>i));
    push(x, T1, M8);
    push(mem0, MB0, 2097152);
    for (int b=0;b<8;++b) push(mem1 + (long)b*524288 + 262144, MB1 + (long)b*262144, 262144);
    for (int b=0;b<8;++b) push(mem2 + (long)b*1048576 + 786432, MB2 + (long)b*262144, 262144);
    flush();
  }

  // gate = sigmoid(x@sgate^T+b) -> G ; Bx -> BX
  hgemm_k<1,0,false,1><<<dim3(1,64,1),256,0,stream>>>(T1,0,0,1024, w_sg,0,0,1024,
      G,nullptr,0,0,128,0, sgate_b,nullptr,nullptr, 1.f, 1024);
  hgemm_k<0,0,false,1><<<dim3(1,64,1),256,0,stream>>>(T1,0,0,1024, w_Bw,0,0,1024,
      BX,nullptr,0,0,128,0, nullptr,nullptr,nullptr, 1.f, 1024);
  // scan -> STb (f16)
  scan_k<<<1024,64,0,stream>>>(G,BX,A_log,STb);
  // y = states@C_w^T -> A0
  hgemm_k<0,0,false,1><<<dim3(8,64,1),256,0,stream>>>(STb,0,0,128, w_Cw,0,0,128,
      A0,nullptr,0,0,1024,0, nullptr,nullptr,nullptr, 1.f, 128);
  // u1 = y + (D+1)*x
  add_dx_k<<<8192,256,0,stream>>>(A0, x, Dv);
  // t = LN(u1; sln) -> T0 (f16)
  ln_k<<<8192,256,0,stream>>>(A0, nullptr, sln_g, sln_b, nullptr, T0, 1024);
  // x_state = t@outp^T -> A1
  hgemm_k<0,0,false,1><<<dim3(8,64,1),256,0,stream>>>(T0,0,0,1024, w_op,0,0,1024,
      A1,nullptr,0,0,1024,0, outp_b,nullptr,nullptr, 1.f, 1024);
  // x1 = LN(x + x_state; n1) -> A2 (f32) + T0 (f16)
  ln_k<<<8192,256,0,stream>>>(x, A1, n1_g, n1_b, A2, T0, 1024);
  // Q -> T1, K -> CAT[:,0:1024], V -> CAT[:,1024:2048] (all f16)
  hgemm_k<0,1,false,1><<<dim3(8,64,1),256,0,stream>>>(T0,0,0,1024, w_ai,0,0,1024,
      nullptr,T1,0,0,0,1024, attn_in_b,nullptr,nullptr, 1.f, 1024);
  hgemm_k<0,1,false,1><<<dim3(8,64,1),256,0,stream>>>(T0,0,0,1024, w_ai+1048576,0,0,1024,
      nullptr,CAT,0,0,0,2048, attn_in_b+1024,nullptr,nullptr, 1.f, 1024);
  hgemm_k<0,1,false,1><<<dim3(8,64,1),256,0,stream>>>(T0,0,0,1024, w_ai+2097152,0,0,1024,
      nullptr,CAT+1024,0,0,0,2048, attn_in_b+2048,nullptr,nullptr, 1.f, 1024);
  // flash attention, O in-place over Q (T1)
  attn_self_k<<<dim3(4,16,8),256,0,stream>>>(T1, CAT, T1);
  // ao = O@attn_out^T -> A0
  hgemm_k<0,0,false,1><<<dim3(8,64,1),256,0,stream>>>(T1,0,0,1024, w_ao,0,0,1024,
      A0,nullptr,0,0,1024,0, attn_out_b,nullptr,nullptr, 1.f, 1024);
  // x2 = LN(x1 + ao; n2) -> A1 (f32) + CAT[:,0:1024] (f16)
  ln_k<<<8192,256,0,stream>>>(A2, A0, n2_g, n2_b, A1, CAT, 2048);
  // Qr = x2@wq_r^T -> T0 (f16)
  hgemm_k<0,1,false,1><<<dim3(8,64,1),256,0,stream>>>(CAT,0,0,2048, w_ri,0,0,1024,
      nullptr,T0,0,0,0,1024, retr_in_b,nullptr,nullptr, 1.f, 1024);

  // retrieval comps: O accumulated into A0 (f32)
  const u16* MB[3] = {MB0, MB1, MB2};
  const int cdim[3] = {1024, 512, 256};
  for (int i=0;i<3;++i){
    const int c = cdim[i];
    // hidden = relu(mem@w1^T) -> T2 (f16)
    hgemm_k<2,1,false,1><<<dim3(c/128,16,1),256,0,stream>>>(MB[i],0,0,1024, w_c1[i],0,0,1024,
        nullptr,T2,0,0,0,c, cb1[i],nullptr,nullptr, 1.f, 1024);
    // comp = hidden@w2^T -> T3 (f16)
    hgemm_k<0,1,false,1><<<dim3(8,16,1),256,0,stream>>>(T2,0,0,c, w_c2[i],0,0,c,
        nullptr,T3,0,0,0,1024, cb2[i],nullptr,nullptr, 1.f, c);
    // KR = comp@wk_r^T -> T4 (f16)
    hgemm_k<0,1,false,1><<<dim3(8,16,1),256,0,stream>>>(T3,0,0,1024, w_ri+1048576,0,0,1024,
        nullptr,T4,0,0,0,1024, retr_in_b+1024,nullptr,nullptr, 1.f, 1024);
    // VT = (comp@wv_r^T)^T per batch -> T5 [8][1024][256] (f16)
    hgemm_k<0,3,false,1><<<dim3(8,2,8),256,0,stream>>>(T3,262144,0,1024, w_ri+2097152,0,0,1024,
        nullptr,T5,262144,0,0,256, retr_in_b+2048,nullptr,nullptr, 1.f, 1024);
    // scores = Qr@KR^T / 16 -> T1 (f16) [b][h][1024][256]
    hgemm_k<0,1,false,4><<<dim3(2,8,32),256,0,stream>>>(T0,1048576,256,1024, T4,262144,256,1024,
        nullptr,T1,1048576,262144,0,256, nullptr,nullptr,nullptr, 0.0625f, 256);
    softmax256h_k<<<32768,64,0,stream>>>(T1);
    // O += P@V -> A0 (f32)
    if (i==0)
      hgemm_k<0,0,false,4><<<dim3(2,8,32),256,0,stream>>>(T1,1048576,262144,256, T5,262144,65536,256,
          A0,nullptr,1048576,256,1024,0, nullptr,nullptr,nullptr, 1.f, 256);
    else
      hgemm_k<0,0,true,4><<<dim3(2,8,32),256,0,stream>>>(T1,1048576,262144,256, T5,262144,65536,256,
          A0,nullptr,1048576,256,1024,0, nullptr,nullptr,nullptr, 1.f, 256);
  }
  // OC -> f16 (T1)
  cvt_k<<<8192,256,0,stream>>>(A0, T1, M8);
  // combined = (OC/3)@retr_out^T -> A2 (f32) + CAT[:,1024:] (f16)
  hgemm_k<0,2,false,1><<<dim3(8,64,1),256,0,stream>>>(T1,0,0,1024, w_ro,0,0,1024,
      A2,CAT+1024,0,0,1024,2048, retr_out_b,nullptr,nullptr, 1.f/3.f, 1024);
  // gw = sigmoid(cat@mg^T + b); x3 = x2*(1+gw)+(1-gw)*combined -> A0 (f32) + T0 (f16)
  hgemm_k<4,2,false,1><<<dim3(8,64,1),256,0,stream>>>(CAT,0,0,2048, w_mg,0,0,2048,
      A0,T0,0,0,1024,1024, mg_b,A1,A2, 1.f, 2048);
  // FFN, chunked over M (hidden overlays A2)
  for (int ch=0; ch<2; ++ch){
    const long mo = (long)ch*4096*1024;
    hgemm_k<3,1,false,1><<<dim3(32,32,1),256,0,stream>>>(T0+mo,0,0,1024, w_f1,0,0,1024,
        nullptr,FH,0,0,0,4096, ffn_b1,nullptr,nullptr, 1.f, 1024);
    hgemm_k<0,0,false,1><<<dim3(8,32,1),256,0,stream>>>(FH,0,0,4096, w_f2,0,0,4096,
        A1+mo,nullptr,0,0,1024,0, ffn_b2,nullptr,nullptr, 1.f, 4096);
  }
  // out = LN(x3 + ffn; n3)
  ln_k<<<8192,256,0,stream>>>(A0, A1, n3_g, n3_b, out, nullptr, 0);
}

// Round 9
// 1743.118 us; speedup vs baseline: 4.5851x; 1.3179x over previous
//
#include <hip/hip_runtime.h>
#include <hip/hip_bf16.h>

typedef unsigned short u16;
typedef unsigned int u32;
typedef _Float16 f16;
typedef _Float16 h8 __attribute__((ext_vector_type(8)));
typedef _Float16 h4 __attribute__((ext_vector_type(4)));
typedef float f32x4 __attribute__((ext_vector_type(4)));
typedef float f32x16 __attribute__((ext_vector_type(16)));
typedef unsigned short us8 __attribute__((ext_vector_type(8)));

#define DI __device__ __forceinline__

DI float sigmoidf_(float v){ return 1.f/(1.f+__expf(-v)); }
DI u16 f2h(float v){ f16 h=(f16)v; u16 u; __builtin_memcpy(&u,&h,2); return u; }
DI float h2f(u16 u){ f16 h; __builtin_memcpy(&h,&u,2); return (float)h; }
DI u32 pk2(float a, float b){
  auto t = __builtin_amdgcn_cvt_pkrtz(a,b);   // __fp16 ext_vector(2); take bits
  u32 u; __builtin_memcpy(&u,&t,4); return u;
}
DI void pswap(u32 &a, u32 &b){
  asm volatile("v_permlane32_swap_b32 %0, %1" : "+v"(a), "+v"(b));
}

DI void gl16(const void* g, void* l){
  __builtin_amdgcn_global_load_lds((const __attribute__((address_space(1))) unsigned int*)g,
                                   (__attribute__((address_space(3))) unsigned int*)l, 16, 0, 0);
}

// ---------------------------------------------------------------------------
// FP16 MFMA GEMM (NT): C[M,N] = act(scale*(A @ B^T) + bias), A[M,K] f16,
// B[N,K] f16 (weight layout). 128x128 tile, BK=32, 4 waves (2x2), each wave
// 64x64 via 4x4 frags of v_mfma_f32_16x16x32_f16. global_load_lds width-16
// with pre-swizzled global source; XOR-swizzled ds_read_b128 fragments.
// OUT: 0=f32 C, 1=f16 Ch, 2=dual f32+f16, 3=f16 transposed (Ch[col*ldch+row]).
// ACT: 0=none 1=sigmoid 2=relu 3=gelu(exact) 4=sigmoid-gate-combine(aux1,aux2)
// ZH: 1 => z batches via sXb only; 4 => z=(b<<2|h), offsets b*sXb + h*sXh.
// ---------------------------------------------------------------------------
template<int ACT, int OUT, bool ACC, int ZH>
__global__ __launch_bounds__(256)
void hgemm_k(const u16* A, long sAb, long sAh, int lda,
             const u16* B, long sBb, long sBh, int ldb,
             float* Cf, u16* Ch, long sCb, long sCh, int ldc, int ldch,
             const float* __restrict__ bias,
             const float* __restrict__ aux1, const float* __restrict__ aux2,
             float scale, int K)
{
  const int z = blockIdx.z;
  long zb, zh;
  if (ZH==4){ zb = z>>2; zh = z&3; } else { zb = z; zh = 0; }
  A += zb*sAb + zh*sAh;
  B += zb*sBb + zh*sBh;
  if (OUT==0 || OUT==2) Cf += zb*sCb + zh*sCh;
  if (OUT==1 || OUT==3) Ch += zb*sCb + zh*sCh;

  const int bm = blockIdx.y*128, bn = blockIdx.x*128;
  __shared__ u16 Ash[128*32];
  __shared__ u16 Bsh[128*32];
  const int tid = threadIdx.x, wid = tid>>6, lane = tid&63;
  const int wr = wid>>1, wc = wid&1;

  f32x4 acc[4][4];
  #pragma unroll
  for (int i=0;i<4;++i)
    #pragma unroll
    for (int j=0;j<4;++j)
      #pragma unroll
      for (int r=0;r<4;++r) acc[i][j][r]=0.f;

  const int off0 = wid*2048 + lane*16;   // byte offset in 8KB tile (+is*1024)
  const char* Ab = (const char*)A;
  const char* Bb = (const char*)B;

  for (int k0=0; k0<K; k0+=32){
    __syncthreads();
    #pragma unroll
    for (int is=0; is<2; ++is){
      const int off = off0 + is*1024;
      const int row = off>>6;
      const int sl  = (off&63) ^ ((row&3)<<4);   // pre-swizzled source slot
      gl16(Ab + ((long)(bm+row)*lda + k0)*2 + sl, (char*)Ash + off);
      gl16(Bb + ((long)(bn+row)*ldb + k0)*2 + sl, (char*)Bsh + off);
    }
    asm volatile("s_waitcnt vmcnt(0)" ::: "memory");
    __syncthreads();

    const int ko = lane>>4, li = lane&15;
    h8 af[4], bf[4];
    #pragma unroll
    for (int m=0;m<4;++m){
      const int row = wr*64 + m*16 + li;
      af[m] = *(const h8*)((const char*)Ash + row*64 + ((ko^(row&3))<<4));
    }
    #pragma unroll
    for (int n=0;n<4;++n){
      const int row = wc*64 + n*16 + li;
      bf[n] = *(const h8*)((const char*)Bsh + row*64 + ((ko^(row&3))<<4));
    }
    #pragma unroll
    for (int m=0;m<4;++m)
      #pragma unroll
      for (int n=0;n<4;++n)
        acc[m][n] = __builtin_amdgcn_mfma_f32_16x16x32_f16(af[m], bf[n], acc[m][n], 0,0,0);
  }

  const int li = lane&15;
  const int r0 = bm + wr*64 + (lane>>4)*4;
  const int c0 = bn + wc*64 + li;
  #pragma unroll
  for (int n=0;n<4;++n){
    const int col = c0 + n*16;
    const float bv = bias ? bias[col] : 0.f;
    #pragma unroll
    for (int m=0;m<4;++m){
      #pragma unroll
      for (int r=0;r<4;++r){
        const int row = r0 + m*16 + r;
        float v = acc[m][n][r]*scale + bv;
        if (ACT==1)      v = sigmoidf_(v);
        else if (ACT==2) v = fmaxf(v,0.f);
        else if (ACT==3) v = 0.5f*v*(1.f+erff(v*0.70710678118f));
        else if (ACT==4){
          const long ix = (long)row*ldc + col;
          const float gg = sigmoidf_(v);
          v = fmaf(aux1[ix], 1.f+gg, (1.f-gg)*aux2[ix]);
        }
        if (OUT==0){
          const long ix = (long)row*ldc + col;
          Cf[ix] = ACC ? Cf[ix]+v : v;
        } else if (OUT==1){
          Ch[(long)row*ldch + col] = f2h(v);
        } else if (OUT==2){
          Cf[(long)row*ldc + col] = v;
          Ch[(long)row*ldch + col] = f2h(v);
        } else {
          Ch[(long)col*ldch + row] = f2h(v);
        }
      }
    }
  }
}

// ---------------------------------------------------------------------------
// SSM scan (unchanged math, f16 output)
// ---------------------------------------------------------------------------
__global__ __launch_bounds__(64)
void scan_k(const float* __restrict__ G, const float* __restrict__ BX,
            const float* __restrict__ A_log, u16* __restrict__ ST)
{
  const int b = blockIdx.x >> 7, s = blockIdx.x & 127;
  const int lane = threadIdx.x;
  const float Aa = __expf(A_log[s]);
  const long base = ((long)b*1024)*128 + s;
  float g[16], xv[16];
  const int t0 = lane*16;
  #pragma unroll
  for (int k=0;k<16;++k){
    g[k]  = G [base + (long)(t0+k)*128];
    xv[k] = BX[base + (long)(t0+k)*128];
  }
  float bl = 0.f;
  #pragma unroll
  for (int k=0;k<16;++k) bl = fmaf(Aa, bl, g[k]*xv[k]);
  const float A2v=Aa*Aa, A4v=A2v*A2v, A8v=A4v*A4v, A16=A8v*A8v;
  float a = A16, bb = bl;
  #pragma unroll
  for (int d=1; d<64; d<<=1) {
    float ap = __shfl_up(a, d);
    float bp = __shfl_up(bb, d);
    if (lane >= d) { bb = fmaf(bp, a, bb); a = ap * a; }
  }
  float carry = __shfl_up(bb, 1);
  if (lane == 0) carry = 0.f;
  float st = carry;
  #pragma unroll
  for (int k=0;k<16;++k) {
    st = fmaf(Aa, st, g[k]*xv[k]);
    ST[base + (long)(t0+k)*128] = f2h(st);
  }
}

__global__ __launch_bounds__(256)
void add_dx_k(float* __restrict__ y, const float* __restrict__ x, const float* __restrict__ D)
{
  const long f = ((long)blockIdx.x*256 + threadIdx.x)*4;
  const int col = (int)(f & 1023);
  float4 yv = *(float4*)(y + f);
  const float4 xv = *(const float4*)(x + f);
  const float4 dv = *(const float4*)(D + col);
  yv.x = fmaf(dv.x+1.f, xv.x, yv.x);
  yv.y = fmaf(dv.y+1.f, xv.y, yv.y);
  yv.z = fmaf(dv.z+1.f, xv.z, yv.z);
  yv.w = fmaf(dv.w+1.f, xv.w, yv.w);
  *(float4*)(y+f) = yv;
}

// LN over H=1024: outF (f32, optional) and outH (f16, optional, leading dim ldH)
__global__ __launch_bounds__(256)
void ln_k(const float* __restrict__ a, const float* __restrict__ b,
          const float* __restrict__ g, const float* __restrict__ be,
          float* __restrict__ outF, u16* __restrict__ outH, int ldH)
{
  const int row = blockIdx.x, tid = threadIdx.x;
  const long base = (long)row*1024 + tid*4;
  float4 v = *(const float4*)(a + base);
  if (b) {
    const float4 w = *(const float4*)(b + base);
    v.x+=w.x; v.y+=w.y; v.z+=w.z; v.w+=w.w;
  }
  float s  = v.x+v.y+v.z+v.w;
  float ss = v.x*v.x+v.y*v.y+v.z*v.z+v.w*v.w;
  #pragma unroll
  for (int d=32; d; d>>=1){ s += __shfl_xor(s,d); ss += __shfl_xor(ss,d); }
  __shared__ float rs[4], rss[4];
  const int w = tid>>6, lane = tid&63;
  if (lane==0){ rs[w]=s; rss[w]=ss; }
  __syncthreads();
  s  = rs[0]+rs[1]+rs[2]+rs[3];
  ss = rss[0]+rss[1]+rss[2]+rss[3];
  const float mean = s*(1.f/1024.f);
  const float var  = ss*(1.f/1024.f) - mean*mean;
  const float r = rsqrtf(var + 1e-5f);
  const float4 gv = *(const float4*)(g + tid*4);
  const float4 bv = *(const float4*)(be + tid*4);
  float4 o;
  o.x = (v.x-mean)*r*gv.x + bv.x;
  o.y = (v.y-mean)*r*gv.y + bv.y;
  o.z = (v.z-mean)*r*gv.z + bv.z;
  o.w = (v.w-mean)*r*gv.w + bv.w;
  if (outF) *(float4*)(outF + base) = o;
  if (outH){
    ushort4 h; h.x=f2h(o.x); h.y=f2h(o.y); h.z=f2h(o.z); h.w=f2h(o.w);
    *(ushort4*)(outH + (long)row*ldH + tid*4) = h;
  }
}

// ---------------------------------------------------------------------------
// MFMA flash self-attention: NH=16, dh=64, T=1024, f16 in/out.
// Q/O: [8192,1024] f16 (in-place). KV: [8192,2048] f16 (K cols 0..1023, V 1024..).
// 4 waves/block; wave owns 32 q-rows. KVBLK=32.
// QK^T via mfma(A=K,B=Q) -> S^T (col = q = lane&31, softmax lane-local).
// P packed to f16 via cvt_pkrtz + v_permlane32_swap (T12).
// PV via mfma(A=V^T from LDS, B=P^T) -> O^T (col = q, rescale lane-local).
// ---------------------------------------------------------------------------
__global__ __launch_bounds__(256)
void attn_mfma_k(const u16* __restrict__ Q, const u16* __restrict__ KV, u16* __restrict__ O)
{
  const int b = blockIdx.z, h = blockIdx.y, qt = blockIdx.x;
  const int tid = threadIdx.x, wid = tid>>6, lane = tid&63;
  const int lo5 = lane>>5, l31 = lane&31;
  __shared__ u16 Kls[2048];       // 32x64 f16, XOR-swizzled rows (4KB)
  __shared__ u16 VT[64*36];       // V^T [64][36] f16, row stride 72B (4.6KB)

  const int qrow = qt*128 + wid*32 + l31;
  const long qbase = ((long)(b*1024 + qrow))*1024 + h*64;
  h8 qf[4];
  h8 qscale;
  #pragma unroll
  for (int j=0;j<8;++j) qscale[j] = (f16)0.125f;
  #pragma unroll
  for (int s=0;s<4;++s){
    qf[s] = *(const h8*)(Q + qbase + s*16 + lo5*8);
    qf[s] = qf[s] * qscale;               // fold 1/sqrt(dh)
  }
  f32x16 acc0, acc1;
  #pragma unroll
  for (int j=0;j<16;++j){ acc0[j]=0.f; acc1[j]=0.f; }
  float mrun = -1e30f, lrun = 0.f;

  const long kvrow = (long)b*1024*2048 + h*64;
  const int srow = tid>>3, schk = tid&7;   // K staging: 32 rows x 8 chunks
  const int vkv = tid&31, vd8 = tid>>5;    // V staging: 32 kv x 8 d-octets

  for (int t=0; t<32; ++t){
    __syncthreads();
    {
      const us8 k8 = *(const us8*)(KV + kvrow + (long)(t*32 + srow)*2048 + schk*8);
      const int kb = srow*128 + ((schk*16) ^ ((srow&7)<<4));
      *(us8*)((char*)Kls + kb) = k8;
      const us8 v8 = *(const us8*)(KV + kvrow + (long)(t*32 + vkv)*2048 + 1024 + vd8*8);
      #pragma unroll
      for (int j=0;j<8;++j) VT[(vd8*8+j)*36 + vkv] = v8[j];
    }
    __syncthreads();

    // S^T = K . Q^T  (M=kv, N=q), K-dim = dh in 4 slices of 16
    f32x16 st;
    #pragma unroll
    for (int j=0;j<16;++j) st[j]=0.f;
    #pragma unroll
    for (int s=0;s<4;++s){
      const int kb = l31*128 + (((s*32 + lo5*16)) ^ ((l31&7)<<4));
      h8 kf = *(const h8*)((const char*)Kls + kb);
      st = __builtin_amdgcn_mfma_f32_32x32x16_f16(kf, qf[s], st, 0,0,0);
    }

    // online softmax, lane-local q = l31 (16 kv here, 16 in partner lane)
    float tm = st[0];
    #pragma unroll
    for (int j=1;j<16;++j) tm = fmaxf(tm, st[j]);
    tm = fmaxf(tm, __shfl_xor(tm, 32));
    const float mnew = fmaxf(mrun, tm);
    const float corr = __expf(mrun - mnew);
    mrun = mnew;
    float p[16]; float ls = 0.f;
    #pragma unroll
    for (int j=0;j<16;++j){ p[j] = __expf(st[j] - mnew); ls += p[j]; }
    ls += __shfl_xor(ls, 32);
    lrun = fmaf(lrun, corr, ls);
    #pragma unroll
    for (int j=0;j<16;++j){ acc0[j]*=corr; acc1[j]*=corr; }

    // pack P^T fragments: pa0 = kv 0..15, pa1 = kv 16..31
    u32 X0=pk2(p[0],p[1]), X1=pk2(p[2],p[3]), Y0=pk2(p[4],p[5]), Y1=pk2(p[6],p[7]);
    u32 X2=pk2(p[8],p[9]), X3=pk2(p[10],p[11]), Y2=pk2(p[12],p[13]), Y3=pk2(p[14],p[15]);
    pswap(X0,Y0); pswap(X1,Y1); pswap(X2,Y2); pswap(X3,Y3);
    union { u32 u[4]; h8 v; } pa0u, pa1u;
    pa0u.u[0]=X0; pa0u.u[1]=X1; pa0u.u[2]=Y0; pa0u.u[3]=Y1;
    pa1u.u[0]=X2; pa1u.u[1]=X3; pa1u.u[2]=Y2; pa1u.u[3]=Y3;

    // PV: O^T += V^T . P^T ; A-frag lane holds V^T[d = dh*32 + l31][kv slice]
    #pragma unroll
    for (int kvh=0; kvh<2; ++kvh){
      const h8 pa = kvh ? pa1u.v : pa0u.v;
      #pragma unroll
      for (int dh=0; dh<2; ++dh){
        const int base = (dh*32 + l31)*72 + kvh*32 + lo5*16;
        h4 vlo = *(const h4*)((const char*)VT + base);
        h4 vhi = *(const h4*)((const char*)VT + base + 8);
        h8 vf;
        #pragma unroll
        for (int j=0;j<4;++j){ vf[j]=vlo[j]; vf[4+j]=vhi[j]; }
        if (dh==0) acc0 = __builtin_amdgcn_mfma_f32_32x32x16_f16(vf, pa, acc0, 0,0,0);
        else       acc1 = __builtin_amdgcn_mfma_f32_32x32x16_f16(vf, pa, acc1, 0,0,0);
      }
    }
  }

  // epilogue: lane q = l31; d = dh*32 + 8*bb + 4*lo5 + a
  const float inv = 1.f/lrun;
  #pragma unroll
  for (int bb=0; bb<4; ++bb){
    u32 w0 = pk2(acc0[bb*4+0]*inv, acc0[bb*4+1]*inv);
    u32 w1 = pk2(acc0[bb*4+2]*inv, acc0[bb*4+3]*inv);
    *(uint2*)(O + qbase + bb*8 + lo5*4) = make_uint2(w0,w1);
    u32 w2 = pk2(acc1[bb*4+0]*inv, acc1[bb*4+1]*inv);
    u32 w3 = pk2(acc1[bb*4+2]*inv, acc1[bb*4+3]*inv);
    *(uint2*)(O + qbase + 32 + bb*8 + lo5*4) = make_uint2(w2,w3);
  }
}

// softmax over rows of 256, f16 in/out in place, one wave per row
__global__ __launch_bounds__(64)
void softmax256h_k(u16* __restrict__ S)
{
  u16* p = S + (long)blockIdx.x*256 + threadIdx.x*4;
  ushort4 u = *(ushort4*)p;
  float v0=h2f(u.x), v1=h2f(u.y), v2=h2f(u.z), v3=h2f(u.w);
  float m = fmaxf(fmaxf(v0,v1), fmaxf(v2,v3));
  #pragma unroll
  for (int d=32; d; d>>=1) m = fmaxf(m, __shfl_xor(m, d));
  v0=__expf(v0-m); v1=__expf(v1-m); v2=__expf(v2-m); v3=__expf(v3-m);
  float s = v0+v1+v2+v3;
  #pragma unroll
  for (int d=32; d; d>>=1) s += __shfl_xor(s, d);
  const float inv = 1.f/s;
  ushort4 o; o.x=f2h(v0*inv); o.y=f2h(v1*inv); o.z=f2h(v2*inv); o.w=f2h(v3*inv);
  *(ushort4*)p = o;
}

// batched f32 -> f16 conversion (up to 16 tensors per launch)
struct CvtB { const float* s[16]; u16* d[16]; int n[16]; int start[16]; int cnt; };
__global__ __launch_bounds__(256)
void cvtb_k(CvtB cb)
{
  const int bid = blockIdx.x;
  int t = 0;
  #pragma unroll 1
  for (int i=1;i<16;++i) if (i<cb.cnt && bid>=cb.start[i]) t = i;
  const long idx = ((long)(bid - cb.start[t])*256 + threadIdx.x)*4;
  if (idx >= cb.n[t]) return;
  const float4 v = *(const float4*)(cb.s[t]+idx);
  ushort4 o; o.x=f2h(v.x); o.y=f2h(v.y); o.z=f2h(v.z); o.w=f2h(v.w);
  *(ushort4*)(cb.d[t]+idx) = o;
}

__global__ __launch_bounds__(256)
void cvt_k(const float* __restrict__ s, u16* __restrict__ d, long n)
{
  const long idx = ((long)blockIdx.x*256 + threadIdx.x)*4;
  if (idx >= n) return;
  const float4 v = *(const float4*)(s+idx);
  ushort4 o; o.x=f2h(v.x); o.y=f2h(v.y); o.z=f2h(v.z); o.w=f2h(v.w);
  *(ushort4*)(d+idx) = o;
}

extern "C" void kernel_launch(void* const* d_in, const int* in_sizes, int n_in,
                              void* d_out, int out_size, void* d_ws, size_t ws_size,
                              hipStream_t stream)
{
  const float* x         = (const float*)d_in[0];
  const float* mem0      = (const float*)d_in[1];
  const float* mem1      = (const float*)d_in[2];
  const float* mem2      = (const float*)d_in[3];
  const float* A_log     = (const float*)d_in[4];
  const float* B_w       = (const float*)d_in[5];
  const float* C_w       = (const float*)d_in[6];
  const float* Dv        = (const float*)d_in[7];
  const float* sgate_w   = (const float*)d_in[8];
  const float* sgate_b   = (const float*)d_in[9];
  const float* outp_w    = (const float*)d_in[10];
  const float* outp_b    = (const float*)d_in[11];
  const float* sln_g     = (const float*)d_in[12];
  const float* sln_b     = (const float*)d_in[13];
  const float* attn_in_w = (const float*)d_in[14];
  const float* attn_in_b = (const float*)d_in[15];
  const float* attn_out_w= (const float*)d_in[16];
  const float* attn_out_b= (const float*)d_in[17];
  const float* cw1[3] = {(const float*)d_in[18], (const float*)d_in[22], (const float*)d_in[26]};
  const float* cb1[3] = {(const float*)d_in[19], (const float*)d_in[23], (const float*)d_in[27]};
  const float* cw2[3] = {(const float*)d_in[20], (const float*)d_in[24], (const float*)d_in[28]};
  const float* cb2[3] = {(const float*)d_in[21], (const float*)d_in[25], (const float*)d_in[29]};
  const float* retr_in_w = (const float*)d_in[30];
  const float* retr_in_b = (const float*)d_in[31];
  const float* retr_out_w= (const float*)d_in[32];
  const float* retr_out_b= (const float*)d_in[33];
  const float* mg_w  = (const float*)d_in[34];
  const float* mg_b  = (const float*)d_in[35];
  const float* ffn_w1= (const float*)d_in[36];
  const float* ffn_b1= (const float*)d_in[37];
  const float* ffn_w2= (const float*)d_in[38];
  const float* ffn_b2= (const float*)d_in[39];
  const float* n1_g = (const float*)d_in[40];
  const float* n1_b = (const float*)d_in[41];
  const float* n2_g = (const float*)d_in[42];
  const float* n2_b = (const float*)d_in[43];
  const float* n3_g = (const float*)d_in[44];
  const float* n3_b = (const float*)d_in[45];
  float* out = (float*)d_out;

  // ---- workspace layout ----
  const long M8 = 8388608;     // 8192*1024
  float* A0 = (float*)d_ws;
  float* A1 = A0 + M8;
  float* A2 = A1 + M8;
  float* G  = A2 + M8;                 // 8192*128
  float* BX = G + 1048576;
  u16* U    = (u16*)(BX + 1048576);
  u16* T0   = U;                       // 8M f16
  u16* T1   = T0 + M8;                 // 8M f16 (xb / Q->O / P / OCb)
  u16* CAT  = T1 + M8;                 // 8192 x 2048 f16
  u16* STb  = CAT + 2*M8;              // 8192*128
  u16* T2   = STb + 1048576;           // 2048*1024
  u16* T3   = T2 + 2097152;
  u16* T4   = T3 + 2097152;
  u16* T5   = T4 + 2097152;            // VT [8][1024][256]
  u16* MB0  = T5 + 2097152;            // mem f16 [2048,1024] x3
  u16* MB1  = MB0 + 2097152;
  u16* MB2  = MB1 + 2097152;
  u16* Wb   = MB2 + 2097152;
  u16* wp   = Wb;
  auto nx = [&](long n){ u16* p = wp; wp += n; return p; };
  u16* w_sg  = nx(131072);
  u16* w_Bw  = nx(131072);
  u16* w_Cw  = nx(131072);
  u16* w_op  = nx(1048576);
  u16* w_ai  = nx(3145728);
  u16* w_ao  = nx(1048576);
  u16* w_ri  = nx(3145728);
  u16* w_ro  = nx(1048576);
  u16* w_mg  = nx(2097152);
  u16* w_f1  = nx(4194304);
  u16* w_f2  = nx(4194304);
  u16* w_c1[3] = {nx(1048576), nx(524288), nx(262144)};
  u16* w_c2[3] = {nx(1048576), nx(524288), nx(262144)};
  u16* FH = (u16*)A2;                  // FFN hidden overlays A2 (4096x4096 f16)
  const size_t need = (size_t)((char*)wp - (char*)d_ws);
  if (ws_size < need) return;

  // ---- weight / input conversions to f16 ----
  {
    CvtB cb; int k = 0, blk = 0;
    auto flush = [&](){
      if (k){ cb.cnt = k; cvtb_k<<<blk,256,0,stream>>>(cb); k = 0; blk = 0; }
    };
    auto push = [&](const float* s, u16* d, long n){
      if (k == 16) flush();
      cb.s[k]=s; cb.d[k]=d; cb.n[k]=(int)n; cb.start[k]=blk; blk += (int)(n/1024); ++k;
    };
    push(sgate_w, w_sg, 131072); push(B_w, w_Bw, 131072); push(C_w, w_Cw, 131072);
    push(outp_w, w_op, 1048576); push(attn_in_w, w_ai, 3145728);
    push(attn_out_w, w_ao, 1048576); push(retr_in_w, w_ri, 3145728);
    push(retr_out_w, w_ro, 1048576); push(mg_w, w_mg, 2097152);
    push(ffn_w1, w_f1, 4194304); push(ffn_w2, w_f2, 4194304);
    for (int i=0;i<3;++i) push(cw1[i], w_c1[i], (long)(1048576>>i));
    for (int i=0;i<3;++i) push(cw2[i], w_c2[i], (long)(1048576>>i));
    push(x, T1, M8);
    push(mem0, MB0, 2097152);
    for (int b=0;b<8;++b) push(mem1 + (long)b*524288 + 262144, MB1 + (long)b*262144, 262144);
    for (int b=0;b<8;++b) push(mem2 + (long)b*1048576 + 786432, MB2 + (long)b*262144, 262144);
    flush();
  }

  // gate = sigmoid(x@sgate^T+b) -> G ; Bx -> BX
  hgemm_k<1,0,false,1><<<dim3(1,64,1),256,0,stream>>>(T1,0,0,1024, w_sg,0,0,1024,
      G,nullptr,0,0,128,0, sgate_b,nullptr,nullptr, 1.f, 1024);
  hgemm_k<0,0,false,1><<<dim3(1,64,1),256,0,stream>>>(T1,0,0,1024, w_Bw,0,0,1024,
      BX,nullptr,0,0,128,0, nullptr,nullptr,nullptr, 1.f, 1024);
  // scan -> STb (f16)
  scan_k<<<1024,64,0,stream>>>(G,BX,A_log,STb);
  // y = states@C_w^T -> A0
  hgemm_k<0,0,false,1><<<dim3(8,64,1),256,0,stream>>>(STb,0,0,128, w_Cw,0,0,128,
      A0,nullptr,0,0,1024,0, nullptr,nullptr,nullptr, 1.f, 128);
  // u1 = y + (D+1)*x
  add_dx_k<<<8192,256,0,stream>>>(A0, x, Dv);
  // t = LN(u1; sln) -> T0 (f16)
  ln_k<<<8192,256,0,stream>>>(A0, nullptr, sln_g, sln_b, nullptr, T0, 1024);
  // x_state = t@outp^T -> A1
  hgemm_k<0,0,false,1><<<dim3(8,64,1),256,0,stream>>>(T0,0,0,1024, w_op,0,0,1024,
      A1,nullptr,0,0,1024,0, outp_b,nullptr,nullptr, 1.f, 1024);
  // x1 = LN(x + x_state; n1) -> A2 (f32) + T0 (f16)
  ln_k<<<8192,256,0,stream>>>(x, A1, n1_g, n1_b, A2, T0, 1024);
  // Q -> T1, K -> CAT[:,0:1024], V -> CAT[:,1024:2048] (all f16)
  hgemm_k<0,1,false,1><<<dim3(8,64,1),256,0,stream>>>(T0,0,0,1024, w_ai,0,0,1024,
      nullptr,T1,0,0,0,1024, attn_in_b,nullptr,nullptr, 1.f, 1024);
  hgemm_k<0,1,false,1><<<dim3(8,64,1),256,0,stream>>>(T0,0,0,1024, w_ai+1048576,0,0,1024,
      nullptr,CAT,0,0,0,2048, attn_in_b+1024,nullptr,nullptr, 1.f, 1024);
  hgemm_k<0,1,false,1><<<dim3(8,64,1),256,0,stream>>>(T0,0,0,1024, w_ai+2097152,0,0,1024,
      nullptr,CAT+1024,0,0,0,2048, attn_in_b+2048,nullptr,nullptr, 1.f, 1024);
  // MFMA flash attention, O in-place over Q (T1)
  attn_mfma_k<<<dim3(8,16,8),256,0,stream>>>(T1, CAT, T1);
  // ao = O@attn_out^T -> A0
  hgemm_k<0,0,false,1><<<dim3(8,64,1),256,0,stream>>>(T1,0,0,1024, w_ao,0,0,1024,
      A0,nullptr,0,0,1024,0, attn_out_b,nullptr,nullptr, 1.f, 1024);
  // x2 = LN(x1 + ao; n2) -> A1 (f32) + CAT[:,0:1024] (f16)
  ln_k<<<8192,256,0,stream>>>(A2, A0, n2_g, n2_b, A1, CAT, 2048);
  // Qr = x2@wq_r^T -> T0 (f16)
  hgemm_k<0,1,false,1><<<dim3(8,64,1),256,0,stream>>>(CAT,0,0,2048, w_ri,0,0,1024,
      nullptr,T0,0,0,0,1024, retr_in_b,nullptr,nullptr, 1.f, 1024);

  // retrieval comps: O accumulated into A0 (f32)
  const u16* MB[3] = {MB0, MB1, MB2};
  const int cdim[3] = {1024, 512, 256};
  for (int i=0;i<3;++i){
    const int c = cdim[i];
    // hidden = relu(mem@w1^T) -> T2 (f16)
    hgemm_k<2,1,false,1><<<dim3(c/128,16,1),256,0,stream>>>(MB[i],0,0,1024, w_c1[i],0,0,1024,
        nullptr,T2,0,0,0,c, cb1[i],nullptr,nullptr, 1.f, 1024);
    // comp = hidden@w2^T -> T3 (f16)
    hgemm_k<0,1,false,1><<<dim3(8,16,1),256,0,stream>>>(T2,0,0,c, w_c2[i],0,0,c,
        nullptr,T3,0,0,0,1024, cb2[i],nullptr,nullptr, 1.f, c);
    // KR = comp@wk_r^T -> T4 (f16)
    hgemm_k<0,1,false,1><<<dim3(8,16,1),256,0,stream>>>(T3,0,0,1024, w_ri+1048576,0,0,1024,
        nullptr,T4,0,0,0,1024, retr_in_b+1024,nullptr,nullptr, 1.f, 1024);
    // VT = (comp@wv_r^T)^T per batch -> T5 [8][1024][256] (f16)
    hgemm_k<0,3,false,1><<<dim3(8,2,8),256,0,stream>>>(T3,262144,0,1024, w_ri+2097152,0,0,1024,
        nullptr,T5,262144,0,0,256, retr_in_b+2048,nullptr,nullptr, 1.f, 1024);
    // scores = Qr@KR^T / 16 -> T1 (f16) [b][h][1024][256]
    hgemm_k<0,1,false,4><<<dim3(2,8,32),256,0,stream>>>(T0,1048576,256,1024, T4,262144,256,1024,
        nullptr,T1,1048576,262144,0,256, nullptr,nullptr,nullptr, 0.0625f, 256);
    softmax256h_k<<<32768,64,0,stream>>>(T1);
    // O += P@V -> A0 (f32)
    if (i==0)
      hgemm_k<0,0,false,4><<<dim3(2,8,32),256,0,stream>>>(T1,1048576,262144,256, T5,262144,65536,256,
          A0,nullptr,1048576,256,1024,0, nullptr,nullptr,nullptr, 1.f, 256);
    else
      hgemm_k<0,0,true,4><<<dim3(2,8,32),256,0,stream>>>(T1,1048576,262144,256, T5,262144,65536,256,
          A0,nullptr,1048576,256,1024,0, nullptr,nullptr,nullptr, 1.f, 256);
  }
  // OC -> f16 (T1)
  cvt_k<<<8192,256,0,stream>>>(A0, T1, M8);
  // combined = (OC/3)@retr_out^T -> A2 (f32) + CAT[:,1024:] (f16)
  hgemm_k<0,2,false,1><<<dim3(8,64,1),256,0,stream>>>(T1,0,0,1024, w_ro,0,0,1024,
      A2,CAT+1024,0,0,1024,2048, retr_out_b,nullptr,nullptr, 1.f/3.f, 1024);
  // gw = sigmoid(cat@mg^T + b); x3 = x2*(1+gw)+(1-gw)*combined -> A0 (f32) + T0 (f16)
  hgemm_k<4,2,false,1><<<dim3(8,64,1),256,0,stream>>>(CAT,0,0,2048, w_mg,0,0,2048,
      A0,T0,0,0,1024,1024, mg_b,A1,A2, 1.f, 2048);
  // FFN, chunked over M (hidden overlays A2)
  for (int ch=0; ch<2; ++ch){
    const long mo = (long)ch*4096*1024;
    hgemm_k<3,1,false,1><<<dim3(32,32,1),256,0,stream>>>(T0+mo,0,0,1024, w_f1,0,0,1024,
        nullptr,FH,0,0,0,4096, ffn_b1,nullptr,nullptr, 1.f, 1024);
    hgemm_k<0,0,false,1><<<dim3(8,32,1),256,0,stream>>>(FH,0,0,4096, w_f2,0,0,4096,
        A1+mo,nullptr,0,0,1024,0, ffn_b2,nullptr,nullptr, 1.f, 4096);
  }
  // out = LN(x3 + ffn; n3)
  ln_k<<<8192,256,0,stream>>>(A0, A1, n3_g, n3_b, out, nullptr, 0);
}